// Round 2
// baseline (978.836 us; speedup 1.0000x reference)
//
#include <hip/hip_runtime.h>
#include <hip/hip_bf16.h>

#define D_DIM 512
#define P_DIM 1024
#define E_DIM 256
#define OUT_DIM 500
#define STR 36  // LDS row stride in shorts (72 B): 72*r mod 128 is a 16-perm -> conflict-free

typedef __attribute__((ext_vector_type(8))) __bf16 bf16x8;
typedef __attribute__((ext_vector_type(4))) float f32x4;

__device__ __forceinline__ unsigned short f2bf(float f) {
    unsigned u = __builtin_bit_cast(unsigned, f);
    u += 0x7FFFu + ((u >> 16) & 1u);
    return (unsigned short)(u >> 16);
}
__device__ __forceinline__ unsigned pack2(float a, float b) {
    return (unsigned)f2bf(a) | ((unsigned)f2bf(b) << 16);
}

// ================= K1: prep + weight-combine =================
// blocks [0,32):  Wp_t / We_t combine GEMMs (W = kw @ l1half, stored transposed bf16)
// blocks [32,34): bias vectors b_p, b_e
// blocks [34,290):  w2t transpose+cast (l2_w [512][500] -> w2t [512][512] bf16, zero-pad)
// blocks [290,546): cast post -> bf16
// blocks [546,610): cast emoji -> bf16
__global__ __launch_bounds__(256)
void prep_kernel(const float* __restrict__ post, const float* __restrict__ emoji,
                 const float* __restrict__ k1_w, const float* __restrict__ k1_b,
                 const float* __restrict__ k2_w, const float* __restrict__ k2_b,
                 const float* __restrict__ l1_w, const float* __restrict__ l1_b,
                 const float* __restrict__ l2_w,
                 unsigned short* __restrict__ post_bf, unsigned short* __restrict__ emoji_bf,
                 unsigned short* __restrict__ w2t,
                 unsigned short* __restrict__ Wp_t, unsigned short* __restrict__ We_t,
                 float* __restrict__ bp, float* __restrict__ be) {
    __shared__ __align__(16) unsigned short sA[128 * STR];
    __shared__ __align__(16) unsigned short sB[128 * STR];
    __shared__ float ttile[32][33];
    const int bid = blockIdx.x;
    const int t = threadIdx.x;

    if (bid < 32) {
        // ---- combine: C[n][k] = sum_j l1half[j][n] * kw[k][j]  (= (kw@l1half)^T), bf16 out
        const int mat = bid >> 4;
        const int tileId = bid & 15;
        const int n0 = (tileId >> 2) * 128, kk0 = (tileId & 3) * 128;
        const float* srcA = l1_w + (size_t)mat * 512 * 512;    // A'[n][j] = srcA[j*512+n]
        const float* srcB = mat ? k2_w : k1_w;                 // B'[k][j] row-major
        unsigned short* dst = mat ? We_t : Wp_t;

        const int w = t >> 6, l = t & 63;
        const int wm = (w & 1) * 64, wn = (w >> 1) * 64;
        const int lr = l & 15, lq = l >> 4;
        const int ja = t >> 3, nc = (t & 7) * 16;       // A' staging: thread -> j row, 16 n's
        const int rb = t >> 1, jh = (t & 1) * 16;       // B' staging: thread -> k row, 16 j's

        f32x4 acc[4][4];
        #pragma unroll
        for (int a = 0; a < 4; a++)
            #pragma unroll
            for (int b = 0; b < 4; b++) acc[a][b] = (f32x4){0.f, 0.f, 0.f, 0.f};

        for (int jb = 0; jb < 512; jb += 32) {
            f32x4 av[4], bv[4];
            #pragma unroll
            for (int x = 0; x < 4; x++)
                av[x] = *reinterpret_cast<const f32x4*>(&srcA[(jb + ja) * 512 + n0 + nc + x * 4]);
            #pragma unroll
            for (int x = 0; x < 4; x++)
                bv[x] = *reinterpret_cast<const f32x4*>(&srcB[(kk0 + rb) * 512 + jb + jh + x * 4]);
            __syncthreads();
            // A' transposed into LDS: sA[n][j]
            #pragma unroll
            for (int x = 0; x < 4; x++)
                #pragma unroll
                for (int y = 0; y < 4; y++)
                    sA[(nc + x * 4 + y) * STR + ja] = f2bf(av[x][y]);
            uint4 bw0, bw1;
            bw0.x = pack2(bv[0][0], bv[0][1]); bw0.y = pack2(bv[0][2], bv[0][3]);
            bw0.z = pack2(bv[1][0], bv[1][1]); bw0.w = pack2(bv[1][2], bv[1][3]);
            bw1.x = pack2(bv[2][0], bv[2][1]); bw1.y = pack2(bv[2][2], bv[2][3]);
            bw1.z = pack2(bv[3][0], bv[3][1]); bw1.w = pack2(bv[3][2], bv[3][3]);
            *reinterpret_cast<uint4*>(&sB[rb * STR + jh]) = bw0;
            *reinterpret_cast<uint4*>(&sB[rb * STR + jh + 8]) = bw1;
            __syncthreads();
            bf16x8 af[4], bfr[4];
            #pragma unroll
            for (int mi = 0; mi < 4; mi++)
                af[mi] = *reinterpret_cast<const bf16x8*>(&sA[(wm + mi * 16 + lr) * STR + lq * 8]);
            #pragma unroll
            for (int ni = 0; ni < 4; ni++)
                bfr[ni] = *reinterpret_cast<const bf16x8*>(&sB[(wn + ni * 16 + lr) * STR + lq * 8]);
            #pragma unroll
            for (int mi = 0; mi < 4; mi++)
                #pragma unroll
                for (int ni = 0; ni < 4; ni++)
                    acc[mi][ni] = __builtin_amdgcn_mfma_f32_16x16x32_bf16(af[mi], bfr[ni], acc[mi][ni], 0, 0, 0);
        }
        #pragma unroll
        for (int ni = 0; ni < 4; ni++) {
            int k = kk0 + wn + ni * 16 + lr;
            #pragma unroll
            for (int mi = 0; mi < 4; mi++) {
                int n = n0 + wm + mi * 16 + lq * 4;
                #pragma unroll
                for (int rg = 0; rg < 4; rg++)
                    dst[(n + rg) * 512 + k] = f2bf(acc[mi][ni][rg]);
            }
        }
    } else if (bid < 34) {
        // ---- bias: b[n] = sum_k kb[k] * l1half[k][n]  (+ l1_b for emoji side)
        const int which = bid - 32;
        const float* kb = which ? k2_b : k1_b;
        const float* lw = l1_w + (size_t)which * 512 * 512;
        float a0 = 0.f, a1 = 0.f;
        for (int k = 0; k < 512; k++) {
            float s = kb[k];
            a0 += s * lw[k * 512 + t];
            a1 += s * lw[k * 512 + t + 256];
        }
        if (which) { a0 += l1_b[t]; a1 += l1_b[t + 256]; }
        float* dst = which ? be : bp;
        dst[t] = a0; dst[t + 256] = a1;
    } else if (bid < 290) {
        // ---- w2t[n][k] = l2_w[k][n], n zero-padded to 512
        const int wb = bid - 34;
        const int c0 = (wb & 15) * 32, r0 = (wb >> 4) * 32;  // c over OUT(500), r over 512
        const int tx = t & 31, ty = t >> 5;
        #pragma unroll
        for (int s = 0; s < 32; s += 8) {
            int r = r0 + ty + s, c = c0 + tx;
            ttile[ty + s][tx] = (c < OUT_DIM) ? l2_w[r * OUT_DIM + c] : 0.f;
        }
        __syncthreads();
        #pragma unroll
        for (int s = 0; s < 32; s += 8) {
            int c = c0 + ty + s, r = r0 + tx;
            w2t[c * 512 + r] = f2bf(ttile[tx][ty + s]);
        }
    } else if (bid < 546) {
        // ---- cast post
        const int cb = bid - 290;
        const int idx = cb * 2048 + t * 8;
        f32x4 v0 = *reinterpret_cast<const f32x4*>(&post[idx]);
        f32x4 v1 = *reinterpret_cast<const f32x4*>(&post[idx + 4]);
        uint4 o;
        o.x = pack2(v0[0], v0[1]); o.y = pack2(v0[2], v0[3]);
        o.z = pack2(v1[0], v1[1]); o.w = pack2(v1[2], v1[3]);
        *reinterpret_cast<uint4*>(&post_bf[idx]) = o;
    } else {
        // ---- cast emoji
        const int cb = bid - 546;
        const int idx = cb * 2048 + t * 8;
        f32x4 v0 = *reinterpret_cast<const f32x4*>(&emoji[idx]);
        f32x4 v1 = *reinterpret_cast<const f32x4*>(&emoji[idx + 4]);
        uint4 o;
        o.x = pack2(v0[0], v0[1]); o.y = pack2(v0[2], v0[3]);
        o.z = pack2(v1[0], v1[1]); o.w = pack2(v1[2], v1[3]);
        *reinterpret_cast<uint4*>(&emoji_bf[idx]) = o;
    }
}

// ================= K2: projections pp / ee =================
__device__ __forceinline__
void gemm128_body(const unsigned short* __restrict__ A, const unsigned short* __restrict__ Bt,
                  const float* __restrict__ bias, float* __restrict__ Cd,
                  int m0, int n0, unsigned short* sA, unsigned short* sB) {
    const int t = threadIdx.x;
    const int r = t >> 1, kh = (t & 1) * 16;
    const int w = t >> 6, l = t & 63;
    const int wm = (w & 1) * 64, wn = (w >> 1) * 64;
    const int lr = l & 15, lq = l >> 4;

    f32x4 acc[4][4];
    #pragma unroll
    for (int a = 0; a < 4; a++)
        #pragma unroll
        for (int b = 0; b < 4; b++) acc[a][b] = (f32x4){0.f, 0.f, 0.f, 0.f};

    const unsigned short* aRow = &A[(m0 + r) * 512];
    const unsigned short* bRow = &Bt[(n0 + r) * 512];

    for (int k0 = 0; k0 < 512; k0 += 32) {
        uint4 a0 = *reinterpret_cast<const uint4*>(&aRow[k0 + kh]);
        uint4 a1 = *reinterpret_cast<const uint4*>(&aRow[k0 + kh + 8]);
        uint4 b0 = *reinterpret_cast<const uint4*>(&bRow[k0 + kh]);
        uint4 b1 = *reinterpret_cast<const uint4*>(&bRow[k0 + kh + 8]);
        __syncthreads();
        *reinterpret_cast<uint4*>(&sA[r * STR + kh])     = a0;
        *reinterpret_cast<uint4*>(&sA[r * STR + kh + 8]) = a1;
        *reinterpret_cast<uint4*>(&sB[r * STR + kh])     = b0;
        *reinterpret_cast<uint4*>(&sB[r * STR + kh + 8]) = b1;
        __syncthreads();
        bf16x8 af[4], bfr[4];
        #pragma unroll
        for (int mi = 0; mi < 4; mi++)
            af[mi] = *reinterpret_cast<const bf16x8*>(&sA[(wm + mi * 16 + lr) * STR + lq * 8]);
        #pragma unroll
        for (int ni = 0; ni < 4; ni++)
            bfr[ni] = *reinterpret_cast<const bf16x8*>(&sB[(wn + ni * 16 + lr) * STR + lq * 8]);
        #pragma unroll
        for (int mi = 0; mi < 4; mi++)
            #pragma unroll
            for (int ni = 0; ni < 4; ni++)
                acc[mi][ni] = __builtin_amdgcn_mfma_f32_16x16x32_bf16(af[mi], bfr[ni], acc[mi][ni], 0, 0, 0);
    }
    #pragma unroll
    for (int ni = 0; ni < 4; ni++) {
        int n = n0 + wn + ni * 16 + lr;
        float bv = bias[n];
        #pragma unroll
        for (int mi = 0; mi < 4; mi++) {
            int m = m0 + wm + mi * 16 + lq * 4;
            #pragma unroll
            for (int rg = 0; rg < 4; rg++)
                Cd[(m + rg) * 512 + n] = acc[mi][ni][rg] + bv;
        }
    }
}

__global__ __launch_bounds__(256)
void proj_kernel(const unsigned short* __restrict__ post_bf, const unsigned short* __restrict__ emoji_bf,
                 const unsigned short* __restrict__ Wp_t, const unsigned short* __restrict__ We_t,
                 const float* __restrict__ bp, const float* __restrict__ be,
                 float* __restrict__ pp, float* __restrict__ eeb) {
    __shared__ __align__(16) unsigned short sA[128 * STR];
    __shared__ __align__(16) unsigned short sB[128 * STR];
    const int bid = blockIdx.x;
    if (bid < 32)
        gemm128_body(post_bf, Wp_t, bp, pp, (bid >> 2) * 128, (bid & 3) * 128, sA, sB);
    else {
        int b2i = bid - 32;
        gemm128_body(emoji_bf, We_t, be, eeb, (b2i >> 2) * 128, (b2i & 3) * 128, sA, sB);
    }
}

// ================= K3: fused pairwise MLP =================
// M-tile 128 pairs (one i, 128 j), N-tile 256, BK 32; 4 waves of 64M x 128N (4x8 frags).
__global__ __launch_bounds__(256, 2)
void pair_mlp_kernel(const float* __restrict__ pp, const float* __restrict__ ee,
                     const unsigned short* __restrict__ w2t,
                     const float* __restrict__ b2, float* __restrict__ out) {
    __shared__ __align__(16) unsigned short As[128 * STR];
    __shared__ __align__(16) unsigned short Bs[256 * STR];
    __shared__ float pps[D_DIM];

    const int t = threadIdx.x;
    const int mtile = blockIdx.x;        // 0..2047
    const int i = mtile >> 1, j0 = (mtile & 1) * 128;
    const int n0 = blockIdx.y * 256;     // 0 or 256
    const long pairBase = (long)mtile * 128;

    const int w = t >> 6, l = t & 63;
    const int wm = (w & 1) * 64, wn = (w >> 1) * 128;
    const int lr = l & 15, lq = l >> 4;
    const int srow = t >> 2, sc = t & 3;  // staging: row-in-64, 16B chunk

    pps[t] = pp[i * D_DIM + t];
    pps[t + 256] = pp[i * D_DIM + 256 + t];

    f32x4 acc[4][8];
    #pragma unroll
    for (int a = 0; a < 4; a++)
        #pragma unroll
        for (int b = 0; b < 8; b++) acc[a][b] = (f32x4){0.f, 0.f, 0.f, 0.f};

    for (int k0 = 0; k0 < D_DIM; k0 += 32) {
        f32x4 ea[2], eb[2];
        uint4 wv[4];
        #pragma unroll
        for (int rp = 0; rp < 2; rp++) {
            const float* src = &ee[(j0 + rp * 64 + srow) * D_DIM + k0 + sc * 8];
            ea[rp] = *reinterpret_cast<const f32x4*>(src);
            eb[rp] = *reinterpret_cast<const f32x4*>(src + 4);
        }
        #pragma unroll
        for (int rp = 0; rp < 4; rp++)
            wv[rp] = *reinterpret_cast<const uint4*>(&w2t[(n0 + rp * 64 + srow) * 512 + k0 + sc * 8]);
        __syncthreads();
        f32x4 p0 = *reinterpret_cast<const f32x4*>(&pps[k0 + sc * 8]);
        f32x4 p1 = *reinterpret_cast<const f32x4*>(&pps[k0 + sc * 8 + 4]);
        #pragma unroll
        for (int rp = 0; rp < 2; rp++) {
            f32x4 s0 = ea[rp] + p0, s1 = eb[rp] + p1;
            #pragma unroll
            for (int x = 0; x < 4; x++) {
                s0[x] = s0[x] > 0.f ? s0[x] : 0.f;
                s1[x] = s1[x] > 0.f ? s1[x] : 0.f;
            }
            uint4 h;
            h.x = pack2(s0[0], s0[1]); h.y = pack2(s0[2], s0[3]);
            h.z = pack2(s1[0], s1[1]); h.w = pack2(s1[2], s1[3]);
            *reinterpret_cast<uint4*>(&As[(rp * 64 + srow) * STR + sc * 8]) = h;
        }
        #pragma unroll
        for (int rp = 0; rp < 4; rp++)
            *reinterpret_cast<uint4*>(&Bs[(rp * 64 + srow) * STR + sc * 8]) = wv[rp];
        __syncthreads();
        bf16x8 af[4], bfr[8];
        #pragma unroll
        for (int mi = 0; mi < 4; mi++)
            af[mi] = *reinterpret_cast<const bf16x8*>(&As[(wm + mi * 16 + lr) * STR + lq * 8]);
        #pragma unroll
        for (int ni = 0; ni < 8; ni++)
            bfr[ni] = *reinterpret_cast<const bf16x8*>(&Bs[(wn + ni * 16 + lr) * STR + lq * 8]);
        #pragma unroll
        for (int mi = 0; mi < 4; mi++)
            #pragma unroll
            for (int ni = 0; ni < 8; ni++)
                acc[mi][ni] = __builtin_amdgcn_mfma_f32_16x16x32_bf16(af[mi], bfr[ni], acc[mi][ni], 0, 0, 0);
    }

    #pragma unroll
    for (int ni = 0; ni < 8; ni++) {
        int n = n0 + wn + ni * 16 + lr;
        if (n < OUT_DIM) {
            float bv = b2[n];
            #pragma unroll
            for (int mi = 0; mi < 4; mi++) {
                int m = wm + mi * 16 + lq * 4;
                float* op = &out[(pairBase + m) * OUT_DIM + n];
                #pragma unroll
                for (int rg = 0; rg < 4; rg++) {
                    float v = acc[mi][ni][rg] + bv;
                    op[(long)rg * OUT_DIM] = v > 0.f ? v : 0.f;
                }
            }
        }
    }
}

extern "C" void kernel_launch(void* const* d_in, const int* in_sizes, int n_in,
                              void* d_out, int out_size, void* d_ws, size_t ws_size,
                              hipStream_t stream) {
    const float* post  = (const float*)d_in[0];
    const float* emoji = (const float*)d_in[1];
    const float* k1_w  = (const float*)d_in[2];
    const float* k1_b  = (const float*)d_in[3];
    const float* k2_w  = (const float*)d_in[4];
    const float* k2_b  = (const float*)d_in[5];
    const float* l1_w  = (const float*)d_in[6];
    const float* l1_b  = (const float*)d_in[7];
    const float* l2_w  = (const float*)d_in[8];
    const float* l2_b  = (const float*)d_in[9];
    float* out = (float*)d_out;

    char* wp = (char*)d_ws;
    auto alloc = [&](size_t bytes) { char* q = wp; wp += (bytes + 255) & ~(size_t)255; return q; };
    unsigned short* post_bf  = (unsigned short*)alloc(P_DIM * D_DIM * 2);
    unsigned short* emoji_bf = (unsigned short*)alloc(E_DIM * D_DIM * 2);
    unsigned short* w2t      = (unsigned short*)alloc(512 * 512 * 2);
    unsigned short* Wp_t     = (unsigned short*)alloc(512 * 512 * 2);
    unsigned short* We_t     = (unsigned short*)alloc(512 * 512 * 2);
    float* bp  = (float*)alloc(512 * 4);
    float* be  = (float*)alloc(512 * 4);
    float* pp  = (float*)alloc(P_DIM * D_DIM * 4);
    float* eeb = (float*)alloc(E_DIM * D_DIM * 4);

    prep_kernel<<<610, 256, 0, stream>>>(post, emoji, k1_w, k1_b, k2_w, k2_b, l1_w, l1_b, l2_w,
                                         post_bf, emoji_bf, w2t, Wp_t, We_t, bp, be);
    proj_kernel<<<40, 256, 0, stream>>>(post_bf, emoji_bf, Wp_t, We_t, bp, be, pp, eeb);
    pair_mlp_kernel<<<dim3(2048, 2), 256, 0, stream>>>(pp, eeb, w2t, l2_b, out);
}